// Round 1
// baseline (3634.577 us; speedup 1.0000x reference)
//
#include <hip/hip_runtime.h>

#define K_DIM 512
#define C_DIM 4096
#define MT 64            // rows per workgroup
#define CT 128           // codebook cols per tile
#define KT 32            // K-dwords per B staging chunk
#define NKC (K_DIM / KT) // 16
#define NCT (C_DIM / CT) // 32
#define NITER (NCT * NKC)

// One workgroup: 256 threads (16 tx col-groups x 16 ty row-groups),
// thread tile = 4 rows x 8 cols. A fully LDS-resident (swizzled),
// B single-buffered LDS chunk with register prefetch of the next chunk.
__global__ __launch_bounds__(256, 1)
void vq_argmax_gather(const float* __restrict__ x,
                      const float* __restrict__ e,
                      float* __restrict__ out) {
    __shared__ float As[MT][K_DIM];   // 131072 B, chunk-XOR-swizzled rows
    __shared__ float Bs[CT][KT];      //  16384 B, chunk-XOR-swizzled rows

    const int tid = threadIdx.x;
    const int tx  = tid & 15;   // col group: cols tx*8 .. tx*8+7
    const int ty  = tid >> 4;   // row group: rows ty*4 .. ty*4+3
    const size_t row0 = (size_t)blockIdx.x * MT;

    // ---- stage A: 64 rows x 512 floats; float4 chunk kc of row r stored at kc ^ (r&7)
    for (int it = 0; it < 32; ++it) {
        int flat = tid + it * 256;
        int r    = flat >> 7;      // 0..63
        int kc   = flat & 127;     // float4 chunk 0..127
        float4 v = *reinterpret_cast<const float4*>(x + (row0 + r) * K_DIM + kc * 4);
        int pos  = kc ^ (r & 7);
        *reinterpret_cast<float4*>(&As[r][pos * 4]) = v;
    }
    // ---- stage B chunk 0 (ct=0, kk=0)
    for (int it = 0; it < 4; ++it) {
        int flat = tid + it * 256;
        int c    = flat >> 3;      // 0..127
        int kc   = flat & 7;       // float4 chunk 0..7 within KT
        float4 v = *reinterpret_cast<const float4*>(e + (size_t)c * K_DIM + kc * 4);
        int pos  = kc ^ ((c >> 3) & 7);
        *reinterpret_cast<float4*>(&Bs[c][pos * 4]) = v;
    }
    __syncthreads();

    float bestv[4];
    int   bestc[4];
#pragma unroll
    for (int i = 0; i < 4; ++i) { bestv[i] = -1e30f; bestc[i] = 0; }

    float acc[4][8];

#pragma unroll 1
    for (int ic = 0; ic < NITER; ++ic) {
        const int kk = ic & (NKC - 1);   // k-chunk within current col tile
        const int ct = ic >> 4;          // col tile index
        const bool haveNext = (ic + 1 < NITER);

        // prefetch next B chunk into registers (latency hides under compute)
        float4 pf[4];
        int    npos[4], ncol[4];
        if (haveNext) {
            const int nxt = ic + 1;
            const int nkk = nxt & (NKC - 1);
            const int nct = nxt >> 4;
#pragma unroll
            for (int it = 0; it < 4; ++it) {
                int flat = tid + it * 256;
                int c    = flat >> 3;
                int kc   = flat & 7;
                pf[it]   = *reinterpret_cast<const float4*>(
                    e + (size_t)(nct * CT + c) * K_DIM + nkk * KT + kc * 4);
                ncol[it] = c;
                npos[it] = kc ^ ((c >> 3) & 7);
            }
        }

        if (kk == 0) {
#pragma unroll
            for (int i = 0; i < 4; ++i)
#pragma unroll
                for (int j = 0; j < 8; ++j) acc[i][j] = 0.0f;
        }

        // ---- compute: 8 k-substeps of 4 dwords each
#pragma unroll
        for (int kb = 0; kb < KT / 4; ++kb) {
            float4 a[4], b[8];
#pragma unroll
            for (int i = 0; i < 4; ++i) {
                int r   = ty * 4 + i;
                int kcg = kk * (KT / 4) + kb;      // global float4 chunk 0..127
                int pos = kcg ^ (r & 7);
                a[i] = *reinterpret_cast<const float4*>(&As[r][pos * 4]);
            }
#pragma unroll
            for (int j = 0; j < 8; ++j) {
                int c   = tx * 8 + j;
                int pos = kb ^ ((c >> 3) & 7);
                b[j] = *reinterpret_cast<const float4*>(&Bs[c][pos * 4]);
            }
#pragma unroll
            for (int i = 0; i < 4; ++i)
#pragma unroll
                for (int j = 0; j < 8; ++j) {
                    acc[i][j] = fmaf(a[i].x, b[j].x, acc[i][j]);
                    acc[i][j] = fmaf(a[i].y, b[j].y, acc[i][j]);
                    acc[i][j] = fmaf(a[i].z, b[j].z, acc[i][j]);
                    acc[i][j] = fmaf(a[i].w, b[j].w, acc[i][j]);
                }
        }

        // ---- rotate B buffer (single buffer: drain readers, then write)
        if (haveNext) {
            __syncthreads();   // everyone done reading Bs
#pragma unroll
            for (int it = 0; it < 4; ++it)
                *reinterpret_cast<float4*>(&Bs[ncol[it]][npos[it] * 4]) = pf[it];
            __syncthreads();   // Bs holds chunk ic+1
        }

        // ---- per-row argmax for a finished col tile
        if (kk == NKC - 1) {
#pragma unroll
            for (int i = 0; i < 4; ++i) {
                float v = acc[i][0];
                int   c = ct * CT + tx * 8;
#pragma unroll
                for (int j = 1; j < 8; ++j) {
                    int cc = ct * CT + tx * 8 + j;
                    if (acc[i][j] > v) { v = acc[i][j]; c = cc; }   // strict >: first max wins
                }
                // butterfly across the 16-lane tx group (lane bits 0..3)
#pragma unroll
                for (int m = 1; m <= 8; m <<= 1) {
                    float vo = __shfl_xor(v, m);
                    int   co = __shfl_xor(c, m);
                    if (vo > v || (vo == v && co < c)) { v = vo; c = co; }
                }
                if (v > bestv[i] || (v == bestv[i] && c < bestc[i])) {
                    bestv[i] = v; bestc[i] = c;
                }
            }
        }
    }

    // ---- gather: out[row] = e[best[row]] ; 16 lanes of a ty-group copy one row
#pragma unroll
    for (int i = 0; i < 4; ++i) {
        int r = ty * 4 + i;
        const float* erow = e + (size_t)bestc[i] * K_DIM;
        float*       orow = out + (row0 + r) * K_DIM;
        for (int ch = tx; ch < K_DIM / 4; ch += 16) {
            *reinterpret_cast<float4*>(orow + ch * 4) =
                *reinterpret_cast<const float4*>(erow + ch * 4);
        }
    }
}

extern "C" void kernel_launch(void* const* d_in, const int* in_sizes, int n_in,
                              void* d_out, int out_size, void* d_ws, size_t ws_size,
                              hipStream_t stream) {
    const float* x = (const float*)d_in[0];     // [B*N, 512] fp32
    const float* e = (const float*)d_in[1];     // [4096, 512] fp32 (already l2-normalized)
    float* out = (float*)d_out;                 // [B*N, 512] fp32

    const int M = in_sizes[0] / K_DIM;          // 32768
    dim3 grid(M / MT), block(256);
    vq_argmax_gather<<<grid, block, 0, stream>>>(x, e, out);
}

// Round 3
// 240.135 us; speedup vs baseline: 15.1356x; 15.1356x over previous
//
#include <hip/hip_runtime.h>

#define K_DIM  512
#define C_DIM  4096
#define RB     128           // x-rows per workgroup
#define CT     256           // codes per tile
#define NCT    (C_DIM / CT)  // 16
#define NKS    16            // K-steps of 32 per tile
#define ROWB   1024          // bytes per fp16 row (512 * 2)

typedef __attribute__((ext_vector_type(4))) float    f32x4;
typedef _Float16 __attribute__((ext_vector_type(8))) f16x8;

__device__ __forceinline__ void load16(const void* g, void* s) {
    __builtin_amdgcn_global_load_lds(
        (const __attribute__((address_space(1))) unsigned int*)g,
        (__attribute__((address_space(3))) unsigned int*)s, 16, 0, 0);
}

// prepass: x -> X1 fp16 (in d_out), e -> E1 fp16 (in ws)
__global__ __launch_bounds__(256)
void convert_f16(const float* __restrict__ x, const float* __restrict__ e,
                 _Float16* __restrict__ X1, _Float16* __restrict__ E1, int xblocks) {
    const long bid = blockIdx.x;
    const float* src; _Float16* dst; long base;
    if (bid < xblocks) { src = x; dst = X1; base = (bid * 256 + threadIdx.x) * 8L; }
    else               { src = e; dst = E1; base = ((bid - xblocks) * 256 + threadIdx.x) * 8L; }
    float4 v0 = *(const float4*)(src + base);
    float4 v1 = *(const float4*)(src + base + 4);
    f16x8 h;
    h[0] = (_Float16)v0.x; h[1] = (_Float16)v0.y; h[2] = (_Float16)v0.z; h[3] = (_Float16)v0.w;
    h[4] = (_Float16)v1.x; h[5] = (_Float16)v1.y; h[6] = (_Float16)v1.z; h[7] = (_Float16)v1.w;
    *(f16x8*)(dst + base) = h;
}

// fp16 proxy GEMM (swapped operands: MFMA A = codes, B = x-rows) + top-4 candidates
__global__ __launch_bounds__(512, 2)
void vq_gemm(const _Float16* __restrict__ X1,
             const _Float16* __restrict__ E1,
             int* __restrict__ cand) {
    __shared__ __align__(16) unsigned char lds[49152];
    // Es dbuf 2 x 16384 at [0]; Xs dbuf 2 x 8192 at [32768]

    const int tid = threadIdx.x;
    const int l   = tid & 63;
    const int wid = tid >> 6;     // 0..7
    const int wc  = wid & 3;      // code group: codes wc*64..+64 within tile
    const int wr  = wid >> 2;     // row group: rows wr*64..+64
    const long row0 = (long)blockIdx.x * RB;

    auto stage = [&](int buf, int ct, int t) {
        {   // X slice: 128 rows x 64 B; pre-swizzled global source (rule #21)
            int row = wid * 16 + (l >> 2);
            int c   = l & 3;
            const unsigned char* g = (const unsigned char*)X1
                + (row0 + row) * ROWB + t * 64 + ((c ^ (row & 3)) << 4);
            load16(g, lds + 32768 + buf * 8192 + wid * 1024);
        }
#pragma unroll
        for (int h = 0; h < 2; ++h) {   // E slice: 256 rows x 64 B
            int row = wid * 32 + h * 16 + (l >> 2);
            int c   = l & 3;
            const unsigned char* g = (const unsigned char*)E1
                + (long)(ct * CT + row) * ROWB + t * 64 + ((c ^ (row & 3)) << 4);
            load16(g, lds + buf * 16384 + wid * 2048 + h * 1024);
        }
    };

    // per-lane running top-2 (per xn block): covers this lane's 256 codes of its row
    float q0[4], q1[4]; int i0[4], i1[4];
#pragma unroll
    for (int xn = 0; xn < 4; ++xn) { q0[xn] = -3.0e38f; q1[xn] = -3.0e38f; i0[xn] = 0; i1[xn] = 0; }

    f32x4 acc[4][4];
    int cur = 0;
    stage(0, 0, 0);
    __syncthreads();

    for (int ct = 0; ct < NCT; ++ct) {
#pragma unroll
        for (int cm = 0; cm < 4; ++cm)
#pragma unroll
            for (int xn = 0; xn < 4; ++xn) acc[cm][xn] = (f32x4){0.f, 0.f, 0.f, 0.f};

        for (int t = 0; t < NKS; ++t) {
            if (t + 1 < NKS)          stage(cur ^ 1, ct, t + 1);
            else if (ct + 1 < NCT)    stage(cur ^ 1, ct + 1, 0);

            const unsigned char* Es = lds + cur * 16384;
            const unsigned char* Xs = lds + 32768 + cur * 8192;
            const int g = l >> 4;
            f16x8 afr[4], bfr[4];
#pragma unroll
            for (int cm = 0; cm < 4; ++cm) {
                int row = wc * 64 + cm * 16 + (l & 15);
                afr[cm] = *(const f16x8*)(Es + row * 64 + ((g ^ (row & 3)) << 4));
            }
#pragma unroll
            for (int xn = 0; xn < 4; ++xn) {
                int row = wr * 64 + xn * 16 + (l & 15);
                bfr[xn] = *(const f16x8*)(Xs + row * 64 + ((g ^ (row & 3)) << 4));
            }
#pragma unroll
            for (int cm = 0; cm < 4; ++cm)
#pragma unroll
                for (int xn = 0; xn < 4; ++xn)
                    acc[cm][xn] = __builtin_amdgcn_mfma_f32_16x16x32_f16(
                        afr[cm], bfr[xn], acc[cm][xn], 0, 0, 0);

            __syncthreads();
            cur ^= 1;
        }

        // per-tile: insert this tile's 16 values/lane into per-lane top-2
        const int cbase = ct * CT + wc * 64 + (l >> 4) * 4;
#pragma unroll
        for (int xn = 0; xn < 4; ++xn) {
#pragma unroll
            for (int cm = 0; cm < 4; ++cm)
#pragma unroll
                for (int j = 0; j < 4; ++j) {
                    float v = acc[cm][xn][j];
                    int  cc = cbase + cm * 16 + j;
                    bool b0 = v > q0[xn];
                    bool b1 = v > q1[xn];
                    q1[xn] = b1 ? (b0 ? q0[xn] : v)  : q1[xn];
                    i1[xn] = b1 ? (b0 ? i0[xn] : cc) : i1[xn];
                    q0[xn] = b0 ? v  : q0[xn];
                    i0[xn] = b0 ? cc : i0[xn];
                }
        }
    }

    // merge: 32 candidates/row via LDS -> exact top-4 -> cand[]
    __syncthreads();
    float2* cl = (float2*)lds;            // [128 rows][32 slots]
    const int g4 = l >> 4;
#pragma unroll
    for (int xn = 0; xn < 4; ++xn) {
        int rl = wr * 64 + xn * 16 + (l & 15);
        cl[rl * 32 + wc * 8 + g4 * 2 + 0] = make_float2(q0[xn], __int_as_float(i0[xn]));
        cl[rl * 32 + wc * 8 + g4 * 2 + 1] = make_float2(q1[xn], __int_as_float(i1[xn]));
    }
    __syncthreads();

    if (tid < RB) {
        float t0 = -3.0e38f, t1 = -3.0e38f, t2 = -3.0e38f, t3 = -3.0e38f;
        int   u0 = 0, u1 = 0, u2 = 0, u3 = 0;
        for (int k = 0; k < 32; ++k) {
            float2 p = cl[tid * 32 + k];
            float v = p.x; int cc = __float_as_int(p.y);
            bool b0 = v > t0, b1 = v > t1, b2 = v > t2, b3 = v > t3;
            t3 = b3 ? (b2 ? t2 : v)  : t3;  u3 = b3 ? (b2 ? u2 : cc) : u3;
            t2 = b2 ? (b1 ? t1 : v)  : t2;  u2 = b2 ? (b1 ? u1 : cc) : u2;
            t1 = b1 ? (b0 ? t0 : v)  : t1;  u1 = b1 ? (b0 ? u0 : cc) : u1;
            t0 = b0 ? v : t0;               u0 = b0 ? cc : u0;
        }
        int4 w; w.x = u0; w.y = u1; w.z = u2; w.w = u3;
        *(int4*)(cand + (row0 + tid) * 4) = w;
    }
}

// exact fp32 rerank of the 4 candidates + gather e[winner] -> out
__global__ __launch_bounds__(256)
void rerank_gather(const float* __restrict__ x, const float* __restrict__ e,
                   const int* __restrict__ cand, float* __restrict__ out) {
    const int tid = threadIdx.x;
    const int l   = tid & 63;
    const int w   = tid >> 6;
    const long row = (long)blockIdx.x * 4 + w;

    const float* xr = x + row * K_DIM + l * 8;
    f32x4 xv0 = *(const f32x4*)(xr);
    f32x4 xv1 = *(const f32x4*)(xr + 4);

    float d[4]; int c[4];
#pragma unroll
    for (int i = 0; i < 4; ++i) {
        c[i] = cand[row * 4 + i];
        const float* er = e + (long)c[i] * K_DIM + l * 8;
        f32x4 ev0 = *(const f32x4*)(er);
        f32x4 ev1 = *(const f32x4*)(er + 4);
        float s = 0.0f;
        s = fmaf(xv0[0], ev0[0], s); s = fmaf(xv0[1], ev0[1], s);
        s = fmaf(xv0[2], ev0[2], s); s = fmaf(xv0[3], ev0[3], s);
        s = fmaf(xv1[0], ev1[0], s); s = fmaf(xv1[1], ev1[1], s);
        s = fmaf(xv1[2], ev1[2], s); s = fmaf(xv1[3], ev1[3], s);
        d[i] = s;
    }
#pragma unroll
    for (int m = 1; m < 64; m <<= 1)
#pragma unroll
        for (int i = 0; i < 4; ++i) d[i] += __shfl_xor(d[i], m);

    float bv = d[0]; int bc = c[0];
#pragma unroll
    for (int i = 1; i < 4; ++i)
        if (d[i] > bv || (d[i] == bv && c[i] < bc)) { bv = d[i]; bc = c[i]; }

    const float4* src = (const float4*)(e + (long)bc * K_DIM) + l * 2;
    float4*       dst = (float4*)(out + row * K_DIM) + l * 2;
    dst[0] = src[0];
    dst[1] = src[1];
}

extern "C" void kernel_launch(void* const* d_in, const int* in_sizes, int n_in,
                              void* d_out, int out_size, void* d_ws, size_t ws_size,
                              hipStream_t stream) {
    const float* x = (const float*)d_in[0];   // [M, 512] fp32
    const float* e = (const float*)d_in[1];   // [4096, 512] fp32
    float* out = (float*)d_out;

    const int M  = in_sizes[0] / K_DIM;       // 32768
    const int Ce = in_sizes[1] / K_DIM;       // 4096

    _Float16* X1 = (_Float16*)d_out;                                   // 32 MiB, dead before out written
    _Float16* E1 = (_Float16*)d_ws;                                    // 4 MiB
    int* cand    = (int*)((char*)d_ws + (size_t)Ce * K_DIM * 2);       // M*4 ints

    const int xb = M / 4, eb = Ce / 4;
    convert_f16<<<xb + eb, 256, 0, stream>>>(x, e, X1, E1, xb);
    vq_gemm<<<M / RB, 512, 0, stream>>>(X1, E1, cand);
    rerank_gather<<<M / 4, 256, 0, stream>>>(x, e, cand, out);
}

// Round 4
// 230.417 us; speedup vs baseline: 15.7739x; 1.0422x over previous
//
#include <hip/hip_runtime.h>

#define K_DIM  512
#define C_DIM  4096
#define RB     128           // x-rows per workgroup
#define CT     512           // codes per tile
#define NCT    (C_DIM / CT)  // 8
#define NKS    16            // K-steps of 32 per tile
#define ROWB   1024          // bytes per fp16 row (512 * 2)

typedef __attribute__((ext_vector_type(4))) float    f32x4;
typedef _Float16 __attribute__((ext_vector_type(8))) f16x8;

__device__ __forceinline__ void load16(const void* g, void* s) {
    __builtin_amdgcn_global_load_lds(
        (const __attribute__((address_space(1))) unsigned int*)g,
        (__attribute__((address_space(3))) unsigned int*)s, 16, 0, 0);
}

// prepass: x -> X1 fp16 (in d_out), e -> E1 fp16 (in ws)
__global__ __launch_bounds__(256)
void convert_f16(const float* __restrict__ x, const float* __restrict__ e,
                 _Float16* __restrict__ X1, _Float16* __restrict__ E1, int xblocks) {
    const long bid = blockIdx.x;
    const float* src; _Float16* dst; long base;
    if (bid < xblocks) { src = x; dst = X1; base = (bid * 256 + threadIdx.x) * 8L; }
    else               { src = e; dst = E1; base = ((bid - xblocks) * 256 + threadIdx.x) * 8L; }
    float4 v0 = *(const float4*)(src + base);
    float4 v1 = *(const float4*)(src + base + 4);
    f16x8 h;
    h[0] = (_Float16)v0.x; h[1] = (_Float16)v0.y; h[2] = (_Float16)v0.z; h[3] = (_Float16)v0.w;
    h[4] = (_Float16)v1.x; h[5] = (_Float16)v1.y; h[6] = (_Float16)v1.z; h[7] = (_Float16)v1.w;
    *(f16x8*)(dst + base) = h;
}

// fp16 proxy GEMM (swapped operands: MFMA A = codes, B = x-rows) + top-4 candidates.
// 8 waves = 4 code-groups x 2 row-groups; wave tile = 128 codes x 64 rows.
// LDS: Es dbuf 2x32KB at [0]; Xs dbuf 2x8KB at [65536]; 80 KB total (dynamic).
__global__ __launch_bounds__(512, 2)
void vq_gemm(const _Float16* __restrict__ X1,
             const _Float16* __restrict__ E1,
             int* __restrict__ cand) {
    extern __shared__ unsigned char lds[];

    const int tid = threadIdx.x;
    const int l   = tid & 63;
    const int wid = tid >> 6;     // 0..7
    const int wc  = wid & 3;      // code group: codes wc*128..+128 within tile
    const int wr  = wid >> 2;     // row group: rows wr*64..+64
    const long row0 = (long)blockIdx.x * RB;

    // swizzle s(row) = (row>>1)&3: granule (4*row + col) mod 8 becomes a bijection
    // over rows 0..7 -> 2-way residual (free). Applied to BOTH stage source and reads.
    auto stage = [&](int buf, int ct, int t) {
        {   // X slice: 128 rows x 64 B, 1 load16/thread
            int row = wid * 16 + (l >> 2);
            int c   = l & 3;
            const unsigned char* g = (const unsigned char*)X1
                + (row0 + row) * ROWB + t * 64 + ((c ^ ((row >> 1) & 3)) << 4);
            load16(g, lds + 65536 + buf * 8192 + wid * 1024);
        }
#pragma unroll
        for (int h = 0; h < 4; ++h) {   // E slice: 512 rows x 64 B, 4 load16/thread
            int row = wid * 64 + h * 16 + (l >> 2);
            int c   = l & 3;
            const unsigned char* g = (const unsigned char*)E1
                + (long)(ct * CT + row) * ROWB + t * 64 + ((c ^ ((row >> 1) & 3)) << 4);
            load16(g, lds + buf * 32768 + wid * 4096 + h * 1024);
        }
    };

    // per-lane running top-2 (per xn block): covers 256 codes of this lane's row
    float q0[4], q1[4]; int i0[4], i1[4];
#pragma unroll
    for (int xn = 0; xn < 4; ++xn) { q0[xn] = -3.0e38f; q1[xn] = -3.0e38f; i0[xn] = 0; i1[xn] = 0; }

    f32x4 acc[8][4];
    int cur = 0;
    stage(0, 0, 0);
    __syncthreads();

    for (int ct = 0; ct < NCT; ++ct) {
#pragma unroll
        for (int cm = 0; cm < 8; ++cm)
#pragma unroll
            for (int xn = 0; xn < 4; ++xn) acc[cm][xn] = (f32x4){0.f, 0.f, 0.f, 0.f};

        for (int t = 0; t < NKS; ++t) {
            if (t + 1 < NKS)          stage(cur ^ 1, ct, t + 1);
            else if (ct + 1 < NCT)    stage(cur ^ 1, ct + 1, 0);

            const unsigned char* Es = lds + cur * 32768;
            const unsigned char* Xs = lds + 65536 + cur * 8192;
            const int g = l >> 4;
            f16x8 afr[8], bfr[4];
#pragma unroll
            for (int cm = 0; cm < 8; ++cm) {
                int row = wc * 128 + cm * 16 + (l & 15);
                afr[cm] = *(const f16x8*)(Es + row * 64 + ((g ^ ((row >> 1) & 3)) << 4));
            }
#pragma unroll
            for (int xn = 0; xn < 4; ++xn) {
                int row = wr * 64 + xn * 16 + (l & 15);
                bfr[xn] = *(const f16x8*)(Xs + row * 64 + ((g ^ ((row >> 1) & 3)) << 4));
            }
            __builtin_amdgcn_s_setprio(1);
#pragma unroll
            for (int cm = 0; cm < 8; ++cm)
#pragma unroll
                for (int xn = 0; xn < 4; ++xn)
                    acc[cm][xn] = __builtin_amdgcn_mfma_f32_16x16x32_f16(
                        afr[cm], bfr[xn], acc[cm][xn], 0, 0, 0);
            __builtin_amdgcn_s_setprio(0);

            __syncthreads();
            cur ^= 1;
        }

        // insert this tile's 32 values/lane/xn into per-lane top-2
        const int cbase = ct * CT + wc * 128 + (l >> 4) * 4;
#pragma unroll
        for (int xn = 0; xn < 4; ++xn) {
#pragma unroll
            for (int cm = 0; cm < 8; ++cm)
#pragma unroll
                for (int j = 0; j < 4; ++j) {
                    float v = acc[cm][xn][j];
                    int  cc = cbase + cm * 16 + j;
                    bool b0 = v > q0[xn];
                    bool b1 = v > q1[xn];
                    q1[xn] = b1 ? (b0 ? q0[xn] : v)  : q1[xn];
                    i1[xn] = b1 ? (b0 ? i0[xn] : cc) : i1[xn];
                    q0[xn] = b0 ? v  : q0[xn];
                    i0[xn] = b0 ? cc : i0[xn];
                }
        }
    }

    // merge: 32 candidates/row via LDS -> exact top-4 -> cand[]
    __syncthreads();
    float2* cl = (float2*)lds;            // [128 rows][32 slots]
    const int g4 = l >> 4;
#pragma unroll
    for (int xn = 0; xn < 4; ++xn) {
        int rl = wr * 64 + xn * 16 + (l & 15);
        cl[rl * 32 + wc * 8 + g4 * 2 + 0] = make_float2(q0[xn], __int_as_float(i0[xn]));
        cl[rl * 32 + wc * 8 + g4 * 2 + 1] = make_float2(q1[xn], __int_as_float(i1[xn]));
    }
    __syncthreads();

    if (tid < RB) {
        float t0 = -3.0e38f, t1 = -3.0e38f, t2 = -3.0e38f, t3 = -3.0e38f;
        int   u0 = 0, u1 = 0, u2 = 0, u3 = 0;
        for (int k = 0; k < 32; ++k) {
            float2 p = cl[tid * 32 + k];
            float v = p.x; int cc = __float_as_int(p.y);
            bool b0 = v > t0, b1 = v > t1, b2 = v > t2, b3 = v > t3;
            t3 = b3 ? (b2 ? t2 : v)  : t3;  u3 = b3 ? (b2 ? u2 : cc) : u3;
            t2 = b2 ? (b1 ? t1 : v)  : t2;  u2 = b2 ? (b1 ? u1 : cc) : u2;
            t1 = b1 ? (b0 ? t0 : v)  : t1;  u1 = b1 ? (b0 ? u0 : cc) : u1;
            t0 = b0 ? v : t0;               u0 = b0 ? cc : u0;
        }
        int4 w; w.x = u0; w.y = u1; w.z = u2; w.w = u3;
        *(int4*)(cand + (row0 + tid) * 4) = w;
    }
}

// exact fp32 rerank of the 4 candidates + gather e[winner] -> out
__global__ __launch_bounds__(256)
void rerank_gather(const float* __restrict__ x, const float* __restrict__ e,
                   const int* __restrict__ cand, float* __restrict__ out) {
    const int tid = threadIdx.x;
    const int l   = tid & 63;
    const int w   = tid >> 6;
    const long row = (long)blockIdx.x * 4 + w;

    const float* xr = x + row * K_DIM + l * 8;
    f32x4 xv0 = *(const f32x4*)(xr);
    f32x4 xv1 = *(const f32x4*)(xr + 4);

    float d[4]; int c[4];
#pragma unroll
    for (int i = 0; i < 4; ++i) {
        c[i] = cand[row * 4 + i];
        const float* er = e + (long)c[i] * K_DIM + l * 8;
        f32x4 ev0 = *(const f32x4*)(er);
        f32x4 ev1 = *(const f32x4*)(er + 4);
        float s = 0.0f;
        s = fmaf(xv0[0], ev0[0], s); s = fmaf(xv0[1], ev0[1], s);
        s = fmaf(xv0[2], ev0[2], s); s = fmaf(xv0[3], ev0[3], s);
        s = fmaf(xv1[0], ev1[0], s); s = fmaf(xv1[1], ev1[1], s);
        s = fmaf(xv1[2], ev1[2], s); s = fmaf(xv1[3], ev1[3], s);
        d[i] = s;
    }
#pragma unroll
    for (int m = 1; m < 64; m <<= 1)
#pragma unroll
        for (int i = 0; i < 4; ++i) d[i] += __shfl_xor(d[i], m);

    float bv = d[0]; int bc = c[0];
#pragma unroll
    for (int i = 1; i < 4; ++i)
        if (d[i] > bv || (d[i] == bv && c[i] < bc)) { bv = d[i]; bc = c[i]; }

    const float4* src = (const float4*)(e + (long)bc * K_DIM) + l * 2;
    float4*       dst = (float4*)(out + row * K_DIM) + l * 2;
    dst[0] = src[0];
    dst[1] = src[1];
}

extern "C" void kernel_launch(void* const* d_in, const int* in_sizes, int n_in,
                              void* d_out, int out_size, void* d_ws, size_t ws_size,
                              hipStream_t stream) {
    const float* x = (const float*)d_in[0];   // [M, 512] fp32
    const float* e = (const float*)d_in[1];   // [4096, 512] fp32
    float* out = (float*)d_out;

    const int M  = in_sizes[0] / K_DIM;       // 32768
    const int Ce = in_sizes[1] / K_DIM;       // 4096

    _Float16* X1 = (_Float16*)d_out;                                   // 32 MiB, dead before out written
    _Float16* E1 = (_Float16*)d_ws;                                    // 4 MiB
    int* cand    = (int*)((char*)d_ws + (size_t)Ce * K_DIM * 2);       // M*4 ints

    const int xb = M / 4, eb = Ce / 4;
    convert_f16<<<xb + eb, 256, 0, stream>>>(x, e, X1, E1, xb);
    vq_gemm<<<M / RB, 512, 81920, stream>>>(X1, E1, cand);
    rerank_gather<<<M / 4, 256, 0, stream>>>(x, e, cand, out);
}